// Round 4
// baseline (419.036 us; speedup 1.0000x reference)
//
#include <hip/hip_runtime.h>

typedef _Float16 h2_t __attribute__((ext_vector_type(2)));
typedef _Float16 h4_t __attribute__((ext_vector_type(4)));
typedef _Float16 h8_t __attribute__((ext_vector_type(8)));
typedef __fp16 fp16x2 __attribute__((ext_vector_type(2)));
typedef float f32x16 __attribute__((ext_vector_type(16)));

// ---------------- helpers ----------------

__device__ __forceinline__ h2_t pkrtz(float a, float b) {
  union { fp16x2 f; h2_t h; } u;
  u.f = __builtin_amdgcn_cvt_pkrtz(a, b);
  return u.h;
}

__device__ __forceinline__ unsigned pk_u(float a, float b) {
  union { fp16x2 f; unsigned u; } z;
  z.f = __builtin_amdgcn_cvt_pkrtz(a, b);
  return z.u;
}

__device__ __forceinline__ h8_t mk8(unsigned w0, unsigned w1, unsigned w2, unsigned w3) {
  union { unsigned u[4]; h8_t h; } z;
  z.u[0] = w0; z.u[1] = w1; z.u[2] = w2; z.u[3] = w3;
  return z.h;
}

__device__ __forceinline__ float fdot2_(h2_t a, h2_t b, float c) {
#if __has_builtin(__builtin_amdgcn_fdot2)
  return __builtin_amdgcn_fdot2(a, b, c, false);
#else
  return fmaf((float)a[0], (float)b[0], fmaf((float)a[1], (float)b[1], c));
#endif
}

__device__ __forceinline__ h2_t u2h(unsigned u) {
  union { unsigned u; h2_t h; } x; x.u = u; return x.h;
}

// ---------------- K0: h = mean_t x ----------------
__global__ void k_hmean(const float* __restrict__ x, float* __restrict__ h) {
  int bc = blockIdx.x;          // b*64+c, 1024 blocks
  int d = threadIdx.x;          // 256
  const float* xp = x + (size_t)bc * (128 * 256) + d;
  float s = 0.f;
  #pragma unroll 8
  for (int t = 0; t < 128; ++t) s += xp[(size_t)t * 256];
  h[bc * 256 + d] = s * (1.f / 128.f);
}

// ---------------- K1: q = h@wq^T, k = h@wk^T ----------------
__global__ void k_qk(const float* __restrict__ h, const float* __restrict__ wq,
                     const float* __restrict__ wk, float* __restrict__ q,
                     float* __restrict__ k) {
  int gid = blockIdx.x * 256 + threadIdx.x;  // 65536 total
  int isK = gid >> 15;
  int e = gid & 32767;       // (b*64+i)*32 + kk
  int kk = e & 31;
  int bi = e >> 5;
  const float4* h4 = (const float4*)(h + bi * 256);
  const float4* w4 = (const float4*)((isK ? wk : wq) + kk * 256);
  float s = 0.f;
  #pragma unroll 4
  for (int d = 0; d < 64; ++d) {
    float4 a = h4[d], bv = w4[d];
    s = fmaf(a.x, bv.x, s); s = fmaf(a.y, bv.y, s);
    s = fmaf(a.z, bv.z, s); s = fmaf(a.w, bv.w, s);
  }
  (isK ? k : q)[e] = s;
}

// ---------------- K2: sim -> tanh -> delta_a out, top-8 -> column masks ----------------
__global__ void k_adj(const float* __restrict__ q, const float* __restrict__ k,
                      const float* __restrict__ sadj, float* __restrict__ dout,
                      unsigned long long* __restrict__ cmask) {
  __shared__ float qs[64][33], ks[64][33];
  __shared__ float ad[64][65];
  __shared__ unsigned long long rowm[64];
  int b = blockIdx.x, tid = threadIdx.x;   // 16 blocks x 256
  for (int r = 0; r < 8; ++r) {
    int idx = r * 256 + tid;
    qs[idx >> 5][idx & 31] = q[b * 2048 + idx];
    ks[idx >> 5][idx & 31] = k[b * 2048 + idx];
  }
  __syncthreads();
  const float rs = 0.17677669529663687f;  // 1/sqrt(32)
  for (int r = 0; r < 16; ++r) {
    int idx = r * 256 + tid;
    int i = idx >> 6, j = idx & 63;
    float s = 0.f;
    #pragma unroll 8
    for (int kk = 0; kk < 32; ++kk) s = fmaf(qs[i][kk], ks[j][kk], s);
    float dv = tanhf(s * rs);
    dout[b * 4096 + idx] = dv;      // delta_a output (fp32)
    ad[i][j] = sadj[idx] + dv;      // adaptive
  }
  __syncthreads();
  if (tid < 64) {
    unsigned long long sel = 0ull;
    for (int p = 0; p < 8; ++p) {
      float best = -1.f; int bj = 0;
      for (int j = 0; j < 64; ++j) {
        if ((sel >> j) & 1ull) continue;
        float v = fabsf(ad[tid][j]);
        if (v > best) { best = v; bj = j; }
      }
      sel |= 1ull << bj;
    }
    rowm[tid] = sel;
  }
  __syncthreads();
  if (tid < 64) {
    unsigned long long cmv = 1ull << tid;   // self loop
    for (int i = 0; i < 64; ++i) cmv |= ((rowm[i] >> tid) & 1ull) << i;
    cmask[b * 64 + tid] = cmv;
  }
}

// ---------------- K3: vsd16[h]=att_src[h].G_h (rows 0-7), att_dst (rows 8-15), f16 ----------------
__global__ void k_vsd(const float* __restrict__ glin, const float* __restrict__ asrc,
                      const float* __restrict__ adst, _Float16* __restrict__ vsd16) {
  int hh = blockIdx.x, d = threadIdx.x;  // 8 x 256
  const float* gb = glin + (size_t)hh * 65536;
  float s = 0.f, t = 0.f;
  for (int f = 0; f < 256; ++f) {
    float g = gb[f * 256 + d];
    s = fmaf(asrc[hh * 256 + f], g, s);
    t = fmaf(adst[hh * 256 + f], g, t);
  }
  vsd16[hh * 256 + d] = (_Float16)s;
  vsd16[(8 + hh) * 256 + d] = (_Float16)t;
}

// ---------------- K4: rearrange gat_lin into per-fragment f16 order ----------------
// 16B chunk gid: lane=gid&63, fg=(gid>>6)&3, FID=gid>>8; ft=FID&1, kk=(FID>>1)&3, s=FID>>3
// content: G[h=s>>2][f = fg*64+ft*32+(lane&31)][d = (s&3)*64 + kk*16 + (lane>>5)*8 + 0..7]
__global__ void k_grearr(const float* __restrict__ g, _Float16* __restrict__ o) {
  int gid = blockIdx.x * 256 + threadIdx.x;   // 65536
  int lane = gid & 63;
  int fg = (gid >> 6) & 3;
  int FID = gid >> 8;
  int ft = FID & 1, kk = (FID >> 1) & 3, s = FID >> 3;
  int h = s >> 2, dc = s & 3;
  int l5 = lane & 31, hi = lane >> 5;
  int f = fg * 64 + ft * 32 + l5;
  int d0 = dc * 64 + kk * 16 + hi * 8;
  const float* src = g + ((size_t)(h * 256 + f) << 8) + d0;
  float4 a = *(const float4*)src;
  float4 bq = *(const float4*)(src + 4);
  h8_t v;
  v[0] = (_Float16)a.x;  v[1] = (_Float16)a.y;  v[2] = (_Float16)a.z;  v[3] = (_Float16)a.w;
  v[4] = (_Float16)bq.x; v[5] = (_Float16)bq.y; v[6] = (_Float16)bq.z; v[7] = (_Float16)bq.w;
  *(h8_t*)(o + (size_t)gid * 8) = v;
}

// ---------------- K5: main fused GAT per (b,t) ----------------
// 512 threads = 8 waves, wave w: mg=w&1 (i-half), fg=w>>1 (f-quarter of 64).
// Main loop: zero barriers, zero LDS ops on operand path.
//   GEMM-A: WX[i-half][f-quarter] = X.G_h^T, A (X) persistent VGPR, B (G) streamed global->VGPR.
//   B2 (WX^T frag) built in-register via cvt_pkrtz + shfl_xor(32).
//   A2 (alpha) built in-lane via precomputed per-column OFF = -log2(sum)-m*1.4427.
//   GEMM-B partial over i-half -> cross-mg reduce via LDS at epilogue.
// LDS: XR 32K @0 | AS 2K @32768 | AD 2K @34816 | OFF 2K @36864 | RED 64K @40960
__global__ __launch_bounds__(512) void k_main(
    const float* __restrict__ x, const _Float16* __restrict__ vsd16,
    const unsigned long long* __restrict__ cmask,
    const _Float16* __restrict__ g16r, const float* __restrict__ bias,
    float* __restrict__ out)
{
  __shared__ __align__(16) char LDS[106496];
  char* XR   = LDS;
  float* ASp = (float*)(LDS + 32768);
  float* ADp = (float*)(LDS + 34816);
  float* OFFp= (float*)(LDS + 36864);
  char* RED  = LDS + 40960;

  const int tid = threadIdx.x;
  const int lane = tid & 63;
  const int w = __builtin_amdgcn_readfirstlane(tid >> 6);
  const int hi = lane >> 5;
  const int l5 = lane & 31;
  const int l7 = lane & 7;
  const int mg = w & 1;
  const int fg = w >> 1;
  const int bt = blockIdx.x;
  const int b = bt >> 7, t = bt & 127;

  const char* gb0 = (const char*)g16r + fg * 1024 + lane * 16;

  // preload G step 0 into buffer A (overlaps X staging)
  h8_t GA[8], GB[8];
  #pragma unroll
  for (int q = 0; q < 8; ++q) GA[q] = *(const h8_t*)(gb0 + q * 4096);

  // column masks for this lane's two target columns (j = l5, 32+l5)
  const unsigned long long cm0 = cmask[b * 64 + l5];
  const unsigned long long cm1 = cmask[b * 64 + 32 + l5];
  // pre-shifted 8-bit mask windows per (jt, kbl): bits e of P-range
  const int shb = mg * 32 + hi * 8;
  const unsigned mb00 = (unsigned)(cm0 >> shb)        & 0xffu;
  const unsigned mb01 = (unsigned)(cm0 >> (shb + 16)) & 0xffu;
  const unsigned mb10 = (unsigned)(cm1 >> shb)        & 0xffu;
  const unsigned mb11 = (unsigned)(cm1 >> (shb + 16)) & 0xffu;

  // stage X[b,:,t,:] -> XR f16 swizzled (rows w*8..w*8+7, lane covers d)
  #pragma unroll
  for (int r = 0; r < 8; ++r) {
    int i = w * 8 + r;
    const float4 v = *(const float4*)(x + (((size_t)(b * 64 + i) * 128 + t) << 8) + lane * 4);
    h2_t p0 = pkrtz(v.x, v.y);
    h2_t p1 = pkrtz(v.z, v.w);
    h4_t hv; hv[0] = p0[0]; hv[1] = p0[1]; hv[2] = p1[0]; hv[3] = p1[1];
    int db = lane >> 1;
    int off = i * 512 + (((db & 24) | ((db ^ (i & 7)) & 7)) << 4) + ((lane & 1) << 3);
    *(h4_t*)(XR + off) = hv;
  }
  __syncthreads();   // XR visible everywhere

  // A-fragments (X rows mg*32+l5), persistent across all heads: 16 x 4 VGPR
  h8_t Af[16];
  {
    int i = mg * 32 + l5;
    #pragma unroll
    for (int k = 0; k < 16; ++k) {
      int db = k * 2 + hi;
      Af[k] = *(const h8_t*)(XR + i * 512 + (((db & 24) | ((db ^ l7) & 7)) << 4));
    }
  }

  // scores: thread (h=w, i=lane) -> AS, AD
  {
    float a_s = 0.f, a_d = 0.f;
    const unsigned* vsp = (const unsigned*)vsd16 + w * 128;
    const unsigned* vdp = (const unsigned*)vsd16 + (8 + w) * 128;
    #pragma unroll 4
    for (int db = 0; db < 32; ++db) {
      h8_t xv = *(const h8_t*)(XR + lane * 512 + (((db & 24) | ((db ^ l7) & 7)) << 4));
      #pragma unroll
      for (int c = 0; c < 4; ++c) {
        h2_t x2; x2[0] = xv[c * 2]; x2[1] = xv[c * 2 + 1];
        a_s = fdot2_(x2, u2h(vsp[db * 4 + c]), a_s);
        a_d = fdot2_(x2, u2h(vdp[db * 4 + c]), a_d);
      }
    }
    ASp[w * 64 + lane] = a_s;
    ADp[w * 64 + lane] = a_d;
  }
  asm volatile("s_waitcnt lgkmcnt(0)" ::: "memory");

  // per-column softmax stats (h=w, j=lane): OFF = -1.4427*m - log2(sum)
  {
    const int j = lane;
    const unsigned long long cmj = cmask[b * 64 + j];
    const float adj = ADp[w * 64 + j];
    float m = -1e30f;
    #pragma unroll 8
    for (int i = 0; i < 64; ++i) {
      float e = ASp[w * 64 + i] + adj;
      e = fmaxf(e, 0.f) + 0.2f * fminf(e, 0.f);
      e = ((cmj >> i) & 1ull) ? e : -1e30f;
      m = fmaxf(m, e);
    }
    float ssum = 0.f;
    #pragma unroll 8
    for (int i = 0; i < 64; ++i) {
      float e = ASp[w * 64 + i] + adj;
      e = fmaxf(e, 0.f) + 0.2f * fminf(e, 0.f);
      e = ((cmj >> i) & 1ull) ? e : -1e30f;
      ssum += exp2f((e - m) * 1.44269504f);
    }
    OFFp[w * 64 + j] = fmaf(-1.44269504f, m, -log2f(ssum));
  }
  __syncthreads();   // AS/AD/OFF visible everywhere

  f32x16 acc00 = {}, acc01 = {}, acc10 = {}, acc11 = {};

  #pragma unroll 1
  for (int h = 0; h < 8; ++h) {
    f32x16 d0 = {}, d1 = {};

    // ---- GEMM-A: 4 dc steps, G double-buffered from global (no LDS) ----
    #pragma unroll
    for (int dc = 0; dc < 4; ++dc) {
      const int s = h * 4 + dc;
      const int sp = (s < 31) ? s + 1 : 31;
      const char* gpp = gb0 + (size_t)sp * 32768;
      if ((dc & 1) == 0) {
        #pragma unroll
        for (int q = 0; q < 8; ++q) GB[q] = *(const h8_t*)(gpp + q * 4096);
        #pragma unroll
        for (int kk = 0; kk < 4; ++kk) {
          d0 = __builtin_amdgcn_mfma_f32_32x32x16_f16(Af[dc * 4 + kk], GA[kk * 2 + 0], d0, 0, 0, 0);
          d1 = __builtin_amdgcn_mfma_f32_32x32x16_f16(Af[dc * 4 + kk], GA[kk * 2 + 1], d1, 0, 0, 0);
        }
      } else {
        #pragma unroll
        for (int q = 0; q < 8; ++q) GA[q] = *(const h8_t*)(gpp + q * 4096);
        #pragma unroll
        for (int kk = 0; kk < 4; ++kk) {
          d0 = __builtin_amdgcn_mfma_f32_32x32x16_f16(Af[dc * 4 + kk], GB[kk * 2 + 0], d0, 0, 0, 0);
          d1 = __builtin_amdgcn_mfma_f32_32x32x16_f16(Af[dc * 4 + kk], GB[kk * 2 + 1], d1, 0, 0, 0);
        }
      }
    }

    // ---- B2 fragments (WX^T) in-register: pk + shfl_xor(32) ----
    h8_t B2[2][2];   // [kbl][ft]
    {
      const bool H = (hi != 0);
      #pragma unroll
      for (int ft = 0; ft < 2; ++ft) {
        const f32x16& dd = ft ? d1 : d0;
        unsigned P0 = pk_u(dd[0], dd[1]),  P1 = pk_u(dd[2], dd[3]);
        unsigned P2 = pk_u(dd[4], dd[5]),  P3 = pk_u(dd[6], dd[7]);
        unsigned P4 = pk_u(dd[8], dd[9]),  P5 = pk_u(dd[10], dd[11]);
        unsigned P6 = pk_u(dd[12], dd[13]), P7 = pk_u(dd[14], dd[15]);
        // kbl = 0
        {
          unsigned Pa = H ? P2 : P0, Pb = H ? P3 : P1;
          unsigned Qa = H ? P0 : P2, Qb = H ? P1 : P3;
          unsigned S0 = (unsigned)__shfl_xor((int)Qa, 32);
          unsigned S1 = (unsigned)__shfl_xor((int)Qb, 32);
          B2[0][ft] = mk8(H ? S0 : Pa, H ? S1 : Pb, H ? Pa : S0, H ? Pb : S1);
        }
        // kbl = 1
        {
          unsigned Pa = H ? P6 : P4, Pb = H ? P7 : P5;
          unsigned Qa = H ? P4 : P6, Qb = H ? P5 : P7;
          unsigned S0 = (unsigned)__shfl_xor((int)Qa, 32);
          unsigned S1 = (unsigned)__shfl_xor((int)Qb, 32);
          B2[1][ft] = mk8(H ? S0 : Pa, H ? S1 : Pb, H ? Pa : S0, H ? Pb : S1);
        }
      }
    }

    // ---- A2 fragments (alpha) in-lane ----
    const float adj0 = ADp[h * 64 + l5];
    const float adj1 = ADp[h * 64 + 32 + l5];
    const float off0 = OFFp[h * 64 + l5];
    const float off1 = OFFp[h * 64 + 32 + l5];
    const float* asp = ASp + h * 64 + mg * 32 + hi * 8;
    float4 asA0 = *(const float4*)(asp);
    float4 asA1 = *(const float4*)(asp + 4);
    float4 asB0 = *(const float4*)(asp + 16);
    float4 asB1 = *(const float4*)(asp + 20);
    float asv[2][8];
    asv[0][0]=asA0.x; asv[0][1]=asA0.y; asv[0][2]=asA0.z; asv[0][3]=asA0.w;
    asv[0][4]=asA1.x; asv[0][5]=asA1.y; asv[0][6]=asA1.z; asv[0][7]=asA1.w;
    asv[1][0]=asB0.x; asv[1][1]=asB0.y; asv[1][2]=asB0.z; asv[1][3]=asB0.w;
    asv[1][4]=asB1.x; asv[1][5]=asB1.y; asv[1][6]=asB1.z; asv[1][7]=asB1.w;

    h8_t A2[2][2];   // [jt][kbl]
    #pragma unroll
    for (int jt = 0; jt < 2; ++jt) {
      const float adj = jt ? adj1 : adj0;
      const float off = jt ? off1 : off0;
      #pragma unroll
      for (int kbl = 0; kbl < 2; ++kbl) {
        const unsigned mb = jt ? (kbl ? mb11 : mb10) : (kbl ? mb01 : mb00);
        float vv[8];
        #pragma unroll
        for (int e = 0; e < 8; ++e) {
          float ee = asv[kbl][e] + adj;
          ee = fmaxf(ee, 0.f) + 0.2f * fminf(ee, 0.f);
          ee = ((mb >> e) & 1u) ? ee : -1e30f;
          vv[e] = exp2f(fmaf(ee, 1.44269504f, off));
        }
        A2[jt][kbl] = mk8(pk_u(vv[0], vv[1]), pk_u(vv[2], vv[3]),
                          pk_u(vv[4], vv[5]), pk_u(vv[6], vv[7]));
      }
    }

    // ---- GEMM-B: partial over this wave's i-half ----
    acc00 = __builtin_amdgcn_mfma_f32_32x32x16_f16(A2[0][0], B2[0][0], acc00, 0, 0, 0);
    acc00 = __builtin_amdgcn_mfma_f32_32x32x16_f16(A2[0][1], B2[1][0], acc00, 0, 0, 0);
    acc01 = __builtin_amdgcn_mfma_f32_32x32x16_f16(A2[0][0], B2[0][1], acc01, 0, 0, 0);
    acc01 = __builtin_amdgcn_mfma_f32_32x32x16_f16(A2[0][1], B2[1][1], acc01, 0, 0, 0);
    acc10 = __builtin_amdgcn_mfma_f32_32x32x16_f16(A2[1][0], B2[0][0], acc10, 0, 0, 0);
    acc10 = __builtin_amdgcn_mfma_f32_32x32x16_f16(A2[1][1], B2[1][0], acc10, 0, 0, 0);
    acc11 = __builtin_amdgcn_mfma_f32_32x32x16_f16(A2[1][0], B2[0][1], acc11, 0, 0, 0);
    acc11 = __builtin_amdgcn_mfma_f32_32x32x16_f16(A2[1][1], B2[1][1], acc11, 0, 0, 0);
  } // h

  // ---- epilogue: cross-mg reduce via LDS, then store ----
  // RED layout: [fg][jt][ft][rq][lane] 16B
  if (mg == 1) {
    #pragma unroll
    for (int jt = 0; jt < 2; ++jt)
      #pragma unroll
      for (int ft = 0; ft < 2; ++ft) {
        const f32x16& a = jt ? (ft ? acc11 : acc10) : (ft ? acc01 : acc00);
        #pragma unroll
        for (int rq = 0; rq < 4; ++rq) {
          float4 v; v.x = a[rq*4+0]; v.y = a[rq*4+1]; v.z = a[rq*4+2]; v.w = a[rq*4+3];
          *(float4*)(RED + (((((fg*2+jt)*2+ft)*4 + rq)*64 + lane) << 4)) = v;
        }
      }
  }
  __syncthreads();
  if (mg == 0) {
    const float bi0 = bias[fg * 64 + l5];
    const float bi1 = bias[fg * 64 + 32 + l5];
    float* ob = out + ((size_t)(b * 64) * 128 + t) * 256;
    #pragma unroll
    for (int jt = 0; jt < 2; ++jt)
      #pragma unroll
      for (int ft = 0; ft < 2; ++ft) {
        const f32x16& a = jt ? (ft ? acc11 : acc10) : (ft ? acc01 : acc00);
        const float bv = ft ? bi1 : bi0;
        const int fcol = fg * 64 + ft * 32 + l5;
        #pragma unroll
        for (int rq = 0; rq < 4; ++rq) {
          float4 p = *(const float4*)(RED + (((((fg*2+jt)*2+ft)*4 + rq)*64 + lane) << 4));
          #pragma unroll
          for (int rr = 0; rr < 4; ++rr) {
            int j = jt * 32 + rr + 8 * rq + 4 * hi;
            float sum = a[rq*4+rr] + ((const float*)&p)[rr];
            ob[(size_t)j * 32768 + fcol] = sum * 0.125f + bv;
          }
        }
      }
  }
}

// ---------------- launch ----------------
extern "C" void kernel_launch(void* const* d_in, const int* in_sizes, int n_in,
                              void* d_out, int out_size, void* d_ws, size_t ws_size,
                              hipStream_t stream) {
  const float* x    = (const float*)d_in[0];
  const float* sadj = (const float*)d_in[1];
  const float* wq   = (const float*)d_in[2];
  const float* wk   = (const float*)d_in[3];
  const float* glin = (const float*)d_in[4];
  const float* asrc = (const float*)d_in[5];
  const float* adst = (const float*)d_in[6];
  const float* bias = (const float*)d_in[7];

  float* out = (float*)d_out;
  float* delta_out = out + (size_t)16 * 64 * 128 * 256;  // 33554432

  char* ws = (char*)d_ws;
  float* h   = (float*)(ws + 0);                  // 1048576 B
  float* q   = (float*)(ws + 1048576);            // 131072 B
  float* k   = (float*)(ws + 1179648);            // 131072 B
  unsigned long long* cm = (unsigned long long*)(ws + 1310720);  // 8192 B
  _Float16* vsd16 = (_Float16*)(ws + 1318912);    // 8192 B
  _Float16* g16r  = (_Float16*)(ws + 1327104);    // 1048576 B

  hipLaunchKernelGGL(k_hmean,  dim3(1024), dim3(256), 0, stream, x, h);
  hipLaunchKernelGGL(k_qk,     dim3(256),  dim3(256), 0, stream, h, wq, wk, q, k);
  hipLaunchKernelGGL(k_adj,    dim3(16),   dim3(256), 0, stream, q, k, sadj, delta_out, cm);
  hipLaunchKernelGGL(k_vsd,    dim3(8),    dim3(256), 0, stream, glin, asrc, adst, vsd16);
  hipLaunchKernelGGL(k_grearr, dim3(256),  dim3(256), 0, stream, glin, g16r);
  hipLaunchKernelGGL(k_main,   dim3(2048), dim3(512), 0, stream, x, vsd16, cm, g16r, bias, out);
}

// Round 5
// 361.342 us; speedup vs baseline: 1.1597x; 1.1597x over previous
//
#include <hip/hip_runtime.h>

typedef _Float16 h2_t __attribute__((ext_vector_type(2)));
typedef _Float16 h4_t __attribute__((ext_vector_type(4)));
typedef _Float16 h8_t __attribute__((ext_vector_type(8)));
typedef __fp16 fp16x2 __attribute__((ext_vector_type(2)));
typedef float f32x16 __attribute__((ext_vector_type(16)));

// ---------------- helpers ----------------

__device__ __forceinline__ h2_t pkrtz(float a, float b) {
  union { fp16x2 f; h2_t h; } u;
  u.f = __builtin_amdgcn_cvt_pkrtz(a, b);
  return u.h;
}

__device__ __forceinline__ unsigned pk_u(float a, float b) {
  union { fp16x2 f; unsigned u; } z;
  z.f = __builtin_amdgcn_cvt_pkrtz(a, b);
  return z.u;
}

__device__ __forceinline__ h8_t mk8(unsigned w0, unsigned w1, unsigned w2, unsigned w3) {
  union { unsigned u[4]; h8_t h; } z;
  z.u[0] = w0; z.u[1] = w1; z.u[2] = w2; z.u[3] = w3;
  return z.h;
}

__device__ __forceinline__ float fdot2_(h2_t a, h2_t b, float c) {
#if __has_builtin(__builtin_amdgcn_fdot2)
  return __builtin_amdgcn_fdot2(a, b, c, false);
#else
  return fmaf((float)a[0], (float)b[0], fmaf((float)a[1], (float)b[1], c));
#endif
}

__device__ __forceinline__ h2_t u2h(unsigned u) {
  union { unsigned u; h2_t h; } x; x.u = u; return x.h;
}

// ---------------- K0: h = mean_t x ----------------
__global__ void k_hmean(const float* __restrict__ x, float* __restrict__ h) {
  int bc = blockIdx.x;          // b*64+c, 1024 blocks
  int d = threadIdx.x;          // 256
  const float* xp = x + (size_t)bc * (128 * 256) + d;
  float s = 0.f;
  #pragma unroll 8
  for (int t = 0; t < 128; ++t) s += xp[(size_t)t * 256];
  h[bc * 256 + d] = s * (1.f / 128.f);
}

// ---------------- K1: q = h@wq^T, k = h@wk^T ----------------
__global__ void k_qk(const float* __restrict__ h, const float* __restrict__ wq,
                     const float* __restrict__ wk, float* __restrict__ q,
                     float* __restrict__ k) {
  int gid = blockIdx.x * 256 + threadIdx.x;  // 65536 total
  int isK = gid >> 15;
  int e = gid & 32767;       // (b*64+i)*32 + kk
  int kk = e & 31;
  int bi = e >> 5;
  const float4* h4 = (const float4*)(h + bi * 256);
  const float4* w4 = (const float4*)((isK ? wk : wq) + kk * 256);
  float s = 0.f;
  #pragma unroll 4
  for (int d = 0; d < 64; ++d) {
    float4 a = h4[d], bv = w4[d];
    s = fmaf(a.x, bv.x, s); s = fmaf(a.y, bv.y, s);
    s = fmaf(a.z, bv.z, s); s = fmaf(a.w, bv.w, s);
  }
  (isK ? k : q)[e] = s;
}

// ---------------- K2: sim -> tanh -> delta_a out, top-8 -> column masks ----------------
__global__ void k_adj(const float* __restrict__ q, const float* __restrict__ k,
                      const float* __restrict__ sadj, float* __restrict__ dout,
                      unsigned long long* __restrict__ cmask) {
  __shared__ float qs[64][33], ks[64][33];
  __shared__ float ad[64][65];
  __shared__ unsigned long long rowm[64];
  int b = blockIdx.x, tid = threadIdx.x;   // 16 blocks x 256
  for (int r = 0; r < 8; ++r) {
    int idx = r * 256 + tid;
    qs[idx >> 5][idx & 31] = q[b * 2048 + idx];
    ks[idx >> 5][idx & 31] = k[b * 2048 + idx];
  }
  __syncthreads();
  const float rs = 0.17677669529663687f;  // 1/sqrt(32)
  for (int r = 0; r < 16; ++r) {
    int idx = r * 256 + tid;
    int i = idx >> 6, j = idx & 63;
    float s = 0.f;
    #pragma unroll 8
    for (int kk = 0; kk < 32; ++kk) s = fmaf(qs[i][kk], ks[j][kk], s);
    float dv = tanhf(s * rs);
    dout[b * 4096 + idx] = dv;      // delta_a output (fp32)
    ad[i][j] = sadj[idx] + dv;      // adaptive
  }
  __syncthreads();
  if (tid < 64) {
    unsigned long long sel = 0ull;
    for (int p = 0; p < 8; ++p) {
      float best = -1.f; int bj = 0;
      for (int j = 0; j < 64; ++j) {
        if ((sel >> j) & 1ull) continue;
        float v = fabsf(ad[tid][j]);
        if (v > best) { best = v; bj = j; }
      }
      sel |= 1ull << bj;
    }
    rowm[tid] = sel;
  }
  __syncthreads();
  if (tid < 64) {
    unsigned long long cmv = 1ull << tid;   // self loop
    for (int i = 0; i < 64; ++i) cmv |= ((rowm[i] >> tid) & 1ull) << i;
    cmask[b * 64 + tid] = cmv;
  }
}

// ---------------- K3: vsd16[h]=att_src[h].G_h (rows 0-7), att_dst (rows 8-15), f16 ----------------
__global__ void k_vsd(const float* __restrict__ glin, const float* __restrict__ asrc,
                      const float* __restrict__ adst, _Float16* __restrict__ vsd16) {
  int hh = blockIdx.x, d = threadIdx.x;  // 8 x 256
  const float* gb = glin + (size_t)hh * 65536;
  float s = 0.f, t = 0.f;
  for (int f = 0; f < 256; ++f) {
    float g = gb[f * 256 + d];
    s = fmaf(asrc[hh * 256 + f], g, s);
    t = fmaf(adst[hh * 256 + f], g, t);
  }
  vsd16[hh * 256 + d] = (_Float16)s;
  vsd16[(8 + hh) * 256 + d] = (_Float16)t;
}

// ---------------- K4: rearrange gat_lin into per-fragment f16 order ----------------
// 16B chunk gid: lane=gid&63, fg=(gid>>6)&3, FID=gid>>8; ft=FID&1, kk=(FID>>1)&3, s=FID>>3
// content: G[h=s>>2][f = fg*64+ft*32+(lane&31)][d = (s&3)*64 + kk*16 + (lane>>5)*8 + 0..7]
__global__ void k_grearr(const float* __restrict__ g, _Float16* __restrict__ o) {
  int gid = blockIdx.x * 256 + threadIdx.x;   // 65536
  int lane = gid & 63;
  int fg = (gid >> 6) & 3;
  int FID = gid >> 8;
  int ft = FID & 1, kk = (FID >> 1) & 3, s = FID >> 3;
  int h = s >> 2, dc = s & 3;
  int l5 = lane & 31, hi = lane >> 5;
  int f = fg * 64 + ft * 32 + l5;
  int d0 = dc * 64 + kk * 16 + hi * 8;
  const float* src = g + ((size_t)(h * 256 + f) << 8) + d0;
  float4 a = *(const float4*)src;
  float4 bq = *(const float4*)(src + 4);
  h8_t v;
  v[0] = (_Float16)a.x;  v[1] = (_Float16)a.y;  v[2] = (_Float16)a.z;  v[3] = (_Float16)a.w;
  v[4] = (_Float16)bq.x; v[5] = (_Float16)bq.y; v[6] = (_Float16)bq.z; v[7] = (_Float16)bq.w;
  *(h8_t*)(o + (size_t)gid * 8) = v;
}

// ---------------- K5: main fused GAT per (b,t) ----------------
// 512 threads = 8 waves, wave w: mg=w&1 (i-half), fg=w>>1 (f-quarter of 64).
// Prologue: X->XR, scores, then ALL-HEADS normalized P -> PT (aliases XR).
// Main loop (zero barriers, zero LDS writes):
//   GEMM-A: A (X) persistent VGPR, B (G) streamed global->VGPR double-buffered.
//   B2 via cvt_pkrtz + shfl_xor(32); A2 via 4x ds_read_b128 from PT.
//   GEMM-B partial over i-half -> cross-mg reduce via LDS (RED aliases PT) at epilogue.
// LDS 68K: [0,64K) XR(32K,prologue) / PT(64K,loop) / RED(64K,epilogue) | ASp 2K | ADp 2K
__global__ __launch_bounds__(512) void k_main(
    const float* __restrict__ x, const _Float16* __restrict__ vsd16,
    const unsigned long long* __restrict__ cmask,
    const _Float16* __restrict__ g16r, const float* __restrict__ bias,
    float* __restrict__ out)
{
  __shared__ __align__(16) char LDS[69632];
  char* XR  = LDS;               // 32K, prologue only
  char* PT  = LDS;               // 64K, aliases XR after prologue
  char* RED = LDS;               // 64K, epilogue aliases PT
  float* ASp = (float*)(LDS + 65536);
  float* ADp = (float*)(LDS + 67584);

  const int tid = threadIdx.x;
  const int lane = tid & 63;
  const int w = __builtin_amdgcn_readfirstlane(tid >> 6);
  const int hi = lane >> 5;
  const int l5 = lane & 31;
  const int l7 = lane & 7;
  const int mg = w & 1;
  const int fg = w >> 1;
  const int bt = blockIdx.x;
  const int b = bt >> 7, t = bt & 127;

  const char* gb0 = (const char*)g16r + fg * 1024 + lane * 16;

  // preload G step 0 into buffer A (overlaps X staging)
  h8_t GA[8], GB[8];
  #pragma unroll
  for (int q = 0; q < 8; ++q) GA[q] = *(const h8_t*)(gb0 + q * 4096);

  // stage X[b,:,t,:] -> XR f16 swizzled (rows w*8..w*8+7, lane covers d)
  #pragma unroll
  for (int r = 0; r < 8; ++r) {
    int i = w * 8 + r;
    const float4 v = *(const float4*)(x + (((size_t)(b * 64 + i) * 128 + t) << 8) + lane * 4);
    h2_t p0 = pkrtz(v.x, v.y);
    h2_t p1 = pkrtz(v.z, v.w);
    h4_t hv; hv[0] = p0[0]; hv[1] = p0[1]; hv[2] = p1[0]; hv[3] = p1[1];
    int db = lane >> 1;
    int off = i * 512 + (((db & 24) | ((db ^ (i & 7)) & 7)) << 4) + ((lane & 1) << 3);
    *(h4_t*)(XR + off) = hv;
  }
  __syncthreads();   // XR visible everywhere

  // A-fragments (X rows mg*32+l5), persistent across all heads: 16 x 4 VGPR
  h8_t Af[16];
  {
    int i = mg * 32 + l5;
    #pragma unroll
    for (int k = 0; k < 16; ++k) {
      int db = k * 2 + hi;
      Af[k] = *(const h8_t*)(XR + i * 512 + (((db & 24) | ((db ^ l7) & 7)) << 4));
    }
  }

  // scores: thread (h=w, i=lane) -> AS, AD
  {
    float a_s = 0.f, a_d = 0.f;
    const unsigned* vsp = (const unsigned*)vsd16 + w * 128;
    const unsigned* vdp = (const unsigned*)vsd16 + (8 + w) * 128;
    #pragma unroll 4
    for (int db = 0; db < 32; ++db) {
      h8_t xv = *(const h8_t*)(XR + lane * 512 + (((db & 24) | ((db ^ l7) & 7)) << 4));
      #pragma unroll
      for (int c = 0; c < 4; ++c) {
        h2_t x2; x2[0] = xv[c * 2]; x2[1] = xv[c * 2 + 1];
        a_s = fdot2_(x2, u2h(vsp[db * 4 + c]), a_s);
        a_d = fdot2_(x2, u2h(vdp[db * 4 + c]), a_d);
      }
    }
    ASp[w * 64 + lane] = a_s;
    ADp[w * 64 + lane] = a_d;
  }
  __syncthreads();   // all XR reads done (Af, scores); ASp/ADp visible

  // P-phase: thread (h=w, j=lane) computes full 64-i softmax, writes normalized P
  // PT layout: [h][j=64][chunk c=0..7 swizzled by j&7][8 f16], row 128 B
  {
    const unsigned long long cmj = cmask[b * 64 + lane];
    const float adj = ADp[w * 64 + lane];
    const float* asr = ASp + w * 64;
    float ssum = 0.f;
    #pragma unroll 8
    for (int i = 0; i < 64; ++i) {
      float e = asr[i] + adj;
      e = fmaxf(e, 0.f) + 0.2f * fminf(e, 0.f);   // leaky_relu(0.2)
      e = ((cmj >> i) & 1ull) ? e : -1e30f;       // mask
      ssum += exp2f(e * 1.44269504f);
    }
    const float rinv = 1.f / ssum;
    #pragma unroll
    for (int c = 0; c < 8; ++c) {
      float vv[8];
      #pragma unroll
      for (int e8 = 0; e8 < 8; ++e8) {
        int i = c * 8 + e8;
        float e = asr[i] + adj;
        e = fmaxf(e, 0.f) + 0.2f * fminf(e, 0.f);
        e = ((cmj >> i) & 1ull) ? e : -1e30f;
        vv[e8] = exp2f(e * 1.44269504f) * rinv;
      }
      *(h8_t*)(PT + w * 8192 + lane * 128 + ((c ^ l7) << 4)) =
          mk8(pk_u(vv[0], vv[1]), pk_u(vv[2], vv[3]),
              pk_u(vv[4], vv[5]), pk_u(vv[6], vv[7]));
    }
  }
  __syncthreads();   // PT ready; XR dead

  f32x16 acc00 = {}, acc01 = {}, acc10 = {}, acc11 = {};

  #pragma unroll 1
  for (int h = 0; h < 8; ++h) {
    f32x16 d0 = {}, d1 = {};

    // ---- GEMM-A: 4 dc steps, G double-buffered from global (no LDS) ----
    #pragma unroll
    for (int dc = 0; dc < 4; ++dc) {
      const int s = h * 4 + dc;
      const int sp = (s < 31) ? s + 1 : 31;
      const char* gpp = gb0 + (size_t)sp * 32768;
      if ((dc & 1) == 0) {
        #pragma unroll
        for (int q = 0; q < 8; ++q) GB[q] = *(const h8_t*)(gpp + q * 4096);
        #pragma unroll
        for (int kk = 0; kk < 4; ++kk) {
          d0 = __builtin_amdgcn_mfma_f32_32x32x16_f16(Af[dc * 4 + kk], GA[kk * 2 + 0], d0, 0, 0, 0);
          d1 = __builtin_amdgcn_mfma_f32_32x32x16_f16(Af[dc * 4 + kk], GA[kk * 2 + 1], d1, 0, 0, 0);
        }
      } else {
        #pragma unroll
        for (int q = 0; q < 8; ++q) GA[q] = *(const h8_t*)(gpp + q * 4096);
        #pragma unroll
        for (int kk = 0; kk < 4; ++kk) {
          d0 = __builtin_amdgcn_mfma_f32_32x32x16_f16(Af[dc * 4 + kk], GB[kk * 2 + 0], d0, 0, 0, 0);
          d1 = __builtin_amdgcn_mfma_f32_32x32x16_f16(Af[dc * 4 + kk], GB[kk * 2 + 1], d1, 0, 0, 0);
        }
      }
    }

    // ---- B2 fragments (WX^T) in-register: pk + shfl_xor(32) ----
    h8_t B2[2][2];   // [kbl][ft]
    {
      const bool H = (hi != 0);
      #pragma unroll
      for (int ft = 0; ft < 2; ++ft) {
        const f32x16& dd = ft ? d1 : d0;
        unsigned P0 = pk_u(dd[0], dd[1]),  P1 = pk_u(dd[2], dd[3]);
        unsigned P2 = pk_u(dd[4], dd[5]),  P3 = pk_u(dd[6], dd[7]);
        unsigned P4 = pk_u(dd[8], dd[9]),  P5 = pk_u(dd[10], dd[11]);
        unsigned P6 = pk_u(dd[12], dd[13]), P7 = pk_u(dd[14], dd[15]);
        // kbl = 0
        {
          unsigned Pa = H ? P2 : P0, Pb = H ? P3 : P1;
          unsigned Qa = H ? P0 : P2, Qb = H ? P1 : P3;
          unsigned S0 = (unsigned)__shfl_xor((int)Qa, 32);
          unsigned S1 = (unsigned)__shfl_xor((int)Qb, 32);
          B2[0][ft] = mk8(H ? S0 : Pa, H ? S1 : Pb, H ? Pa : S0, H ? Pb : S1);
        }
        // kbl = 1
        {
          unsigned Pa = H ? P6 : P4, Pb = H ? P7 : P5;
          unsigned Qa = H ? P4 : P6, Qb = H ? P5 : P7;
          unsigned S0 = (unsigned)__shfl_xor((int)Qa, 32);
          unsigned S1 = (unsigned)__shfl_xor((int)Qb, 32);
          B2[1][ft] = mk8(H ? S0 : Pa, H ? S1 : Pb, H ? Pa : S0, H ? Pb : S1);
        }
      }
    }

    // ---- A2 fragments (alpha) from PT: 4x ds_read_b128 ----
    h8_t A2[2][2];   // [jt][kbl]
    #pragma unroll
    for (int jt = 0; jt < 2; ++jt)
      #pragma unroll
      for (int kbl = 0; kbl < 2; ++kbl) {
        int c = mg * 4 + kbl * 2 + hi;
        A2[jt][kbl] = *(const h8_t*)(PT + h * 8192 + (jt * 32 + l5) * 128 + ((c ^ (l5 & 7)) << 4));
      }

    // ---- GEMM-B: partial over this wave's i-half ----
    acc00 = __builtin_amdgcn_mfma_f32_32x32x16_f16(A2[0][0], B2[0][0], acc00, 0, 0, 0);
    acc00 = __builtin_amdgcn_mfma_f32_32x32x16_f16(A2[0][1], B2[1][0], acc00, 0, 0, 0);
    acc01 = __builtin_amdgcn_mfma_f32_32x32x16_f16(A2[0][0], B2[0][1], acc01, 0, 0, 0);
    acc01 = __builtin_amdgcn_mfma_f32_32x32x16_f16(A2[0][1], B2[1][1], acc01, 0, 0, 0);
    acc10 = __builtin_amdgcn_mfma_f32_32x32x16_f16(A2[1][0], B2[0][0], acc10, 0, 0, 0);
    acc10 = __builtin_amdgcn_mfma_f32_32x32x16_f16(A2[1][1], B2[1][0], acc10, 0, 0, 0);
    acc11 = __builtin_amdgcn_mfma_f32_32x32x16_f16(A2[1][0], B2[0][1], acc11, 0, 0, 0);
    acc11 = __builtin_amdgcn_mfma_f32_32x32x16_f16(A2[1][1], B2[1][1], acc11, 0, 0, 0);
  } // h

  // ---- epilogue: cross-mg reduce via LDS (RED aliases PT), then store ----
  __syncthreads();   // all PT reads done before RED overwrite
  if (mg == 1) {
    #pragma unroll
    for (int jt = 0; jt < 2; ++jt)
      #pragma unroll
      for (int ft = 0; ft < 2; ++ft) {
        const f32x16& a = jt ? (ft ? acc11 : acc10) : (ft ? acc01 : acc00);
        #pragma unroll
        for (int rq = 0; rq < 4; ++rq) {
          float4 v; v.x = a[rq*4+0]; v.y = a[rq*4+1]; v.z = a[rq*4+2]; v.w = a[rq*4+3];
          *(float4*)(RED + (((((fg*2+jt)*2+ft)*4 + rq)*64 + lane) << 4)) = v;
        }
      }
  }
  __syncthreads();
  if (mg == 0) {
    const float bi0 = bias[fg * 64 + l5];
    const float bi1 = bias[fg * 64 + 32 + l5];
    float* ob = out + ((size_t)(b * 64) * 128 + t) * 256;
    #pragma unroll
    for (int jt = 0; jt < 2; ++jt)
      #pragma unroll
      for (int ft = 0; ft < 2; ++ft) {
        const f32x16& a = jt ? (ft ? acc11 : acc10) : (ft ? acc01 : acc00);
        const float bv = ft ? bi1 : bi0;
        const int fcol = fg * 64 + ft * 32 + l5;
        #pragma unroll
        for (int rq = 0; rq < 4; ++rq) {
          float4 p = *(const float4*)(RED + (((((fg*2+jt)*2+ft)*4 + rq)*64 + lane) << 4));
          #pragma unroll
          for (int rr = 0; rr < 4; ++rr) {
            int j = jt * 32 + rr + 8 * rq + 4 * hi;
            float sum = a[rq*4+rr] + ((const float*)&p)[rr];
            ob[(size_t)j * 32768 + fcol] = sum * 0.125f + bv;
          }
        }
      }
  }
}

// ---------------- launch ----------------
extern "C" void kernel_launch(void* const* d_in, const int* in_sizes, int n_in,
                              void* d_out, int out_size, void* d_ws, size_t ws_size,
                              hipStream_t stream) {
  const float* x    = (const float*)d_in[0];
  const float* sadj = (const float*)d_in[1];
  const float* wq   = (const float*)d_in[2];
  const float* wk   = (const float*)d_in[3];
  const float* glin = (const float*)d_in[4];
  const float* asrc = (const float*)d_in[5];
  const float* adst = (const float*)d_in[6];
  const float* bias = (const float*)d_in[7];

  float* out = (float*)d_out;
  float* delta_out = out + (size_t)16 * 64 * 128 * 256;  // 33554432

  char* ws = (char*)d_ws;
  float* h   = (float*)(ws + 0);                  // 1048576 B
  float* q   = (float*)(ws + 1048576);            // 131072 B
  float* k   = (float*)(ws + 1179648);            // 131072 B
  unsigned long long* cm = (unsigned long long*)(ws + 1310720);  // 8192 B
  _Float16* vsd16 = (_Float16*)(ws + 1318912);    // 8192 B
  _Float16* g16r  = (_Float16*)(ws + 1327104);    // 1048576 B

  hipLaunchKernelGGL(k_hmean,  dim3(1024), dim3(256), 0, stream, x, h);
  hipLaunchKernelGGL(k_qk,     dim3(256),  dim3(256), 0, stream, h, wq, wk, q, k);
  hipLaunchKernelGGL(k_adj,    dim3(16),   dim3(256), 0, stream, q, k, sadj, delta_out, cm);
  hipLaunchKernelGGL(k_vsd,    dim3(8),    dim3(256), 0, stream, glin, asrc, adst, vsd16);
  hipLaunchKernelGGL(k_grearr, dim3(256),  dim3(256), 0, stream, glin, g16r);
  hipLaunchKernelGGL(k_main,   dim3(2048), dim3(512), 0, stream, x, vsd16, cm, g16r, bias, out);
}